// Round 1
// baseline (83510.883 us; speedup 1.0000x reference)
//
#include <hip/hip_runtime.h>
#include <cmath>

namespace {

constexpr int Tn = 64;
constexpr int Bn = 512;
constexpr int Xn = 784;
constexpr int Fn = 64;
constexpr int Zn = 64;
constexpr int Hn = 512;

constexpr int BM = 64;
constexpr int BN = 64;
constexpr int BK = 16;

__device__ __forceinline__ float sigmf(float v) { return 1.0f / (1.0f + __expf(-v)); }
__device__ __forceinline__ float splusf(float v) {
  // numerically stable softplus
  return v > 0.0f ? (v + log1pf(__expf(-v))) : log1pf(__expf(v));
}

__device__ __forceinline__ float block_sum(float v) {
  __shared__ float red[4];
  #pragma unroll
  for (int off = 32; off > 0; off >>= 1) v += __shfl_down(v, off, 64);
  const int lane = threadIdx.x & 63;
  const int w = threadIdx.x >> 6;
  if (lane == 0) red[w] = v;
  __syncthreads();
  float s = 0.0f;
  if (threadIdx.x == 0) s = red[0] + red[1] + red[2] + red[3];
  return s;
}

// C[m,n] = act( sum_seg A_seg[m,:] . W_seg[n,:] + bias[n] )
// A_seg row stride == K_seg (all activation buffers are contiguous [*, K]).
// Requires M%64==0, N%64==0, K_seg%16==0.
template <int NSEG, bool RELU>
__global__ __launch_bounds__(256)
void gemm_nt(const float* __restrict__ A0, const float* __restrict__ W0, int ldw0, int K0,
             const float* __restrict__ A1, const float* __restrict__ W1, int ldw1, int K1,
             const float* __restrict__ A2, const float* __restrict__ W2, int ldw2, int K2,
             const float* __restrict__ bias, float* __restrict__ C, int ldc)
{
  __shared__ alignas(16) float As[BK][BM];
  __shared__ alignas(16) float Bs[BK][BN];
  const int tid = threadIdx.x;
  const int tx = tid & 15;
  const int ty = tid >> 4;
  const int m0 = blockIdx.y * BM;
  const int n0 = blockIdx.x * BN;
  const int lr = tid >> 2;
  const int lk = (tid & 3) << 2;
  float acc[4][4] = {};

  for (int seg = 0; seg < NSEG; ++seg) {
    const float* A  = (seg == 0) ? A0 : (seg == 1) ? A1 : A2;
    const float* Wp = (seg == 0) ? W0 : (seg == 1) ? W1 : W2;
    const int ldw   = (seg == 0) ? ldw0 : (seg == 1) ? ldw1 : ldw2;
    const int K     = (seg == 0) ? K0 : (seg == 1) ? K1 : K2;
    const float* ap = A + (size_t)(m0 + lr) * K + lk;
    const float* wp = Wp + (size_t)(n0 + lr) * ldw + lk;
    for (int k0 = 0; k0 < K; k0 += BK) {
      const float4 av = *(const float4*)(ap + k0);
      const float4 wv = *(const float4*)(wp + k0);
      __syncthreads();
      As[lk + 0][lr] = av.x; As[lk + 1][lr] = av.y; As[lk + 2][lr] = av.z; As[lk + 3][lr] = av.w;
      Bs[lk + 0][lr] = wv.x; Bs[lk + 1][lr] = wv.y; Bs[lk + 2][lr] = wv.z; Bs[lk + 3][lr] = wv.w;
      __syncthreads();
      #pragma unroll
      for (int kk = 0; kk < BK; ++kk) {
        const float4 a4 = *(const float4*)&As[kk][ty << 2];
        const float4 b4 = *(const float4*)&Bs[kk][tx << 2];
        const float aa[4] = {a4.x, a4.y, a4.z, a4.w};
        const float bb[4] = {b4.x, b4.y, b4.z, b4.w};
        #pragma unroll
        for (int i = 0; i < 4; ++i)
          #pragma unroll
          for (int j = 0; j < 4; ++j)
            acc[i][j] = fmaf(aa[i], bb[j], acc[i][j]);
      }
    }
  }

  const float4 bv = *(const float4*)&bias[n0 + (tx << 2)];
  const float bb[4] = {bv.x, bv.y, bv.z, bv.w};
  #pragma unroll
  for (int i = 0; i < 4; ++i) {
    float o[4];
    #pragma unroll
    for (int j = 0; j < 4; ++j) {
      o[j] = acc[i][j] + bb[j];
      if (RELU) o[j] = fmaxf(o[j], 0.0f);
    }
    float4 o4 = {o[0], o[1], o[2], o[3]};
    *(float4*)(C + (size_t)(m0 + (ty << 2) + i) * ldc + n0 + (tx << 2)) = o4;
  }
}

// One fused GRU timestep: gi = concat(A0..A_{NSEGI-1}) @ Wih^T, gh = hprev @ Whh^T,
// gate math, writes hnew. Each i-segment has K=Hn; Wih col offset seg*Hn.
template <int NSEGI>
__global__ __launch_bounds__(256)
void gru_step(const float* __restrict__ A0, const float* __restrict__ A1, const float* __restrict__ A2,
              const float* __restrict__ Wih, int ldwih,
              const float* __restrict__ hprev, const float* __restrict__ Whh,
              const float* __restrict__ bih, const float* __restrict__ bhh,
              float* __restrict__ hnew)
{
  __shared__ alignas(16) float As[BK][BM];
  __shared__ alignas(16) float Rs[BK][BN];
  __shared__ alignas(16) float Zs[BK][BN];
  __shared__ alignas(16) float Ns[BK][BN];
  const int tid = threadIdx.x;
  const int tx = tid & 15;
  const int ty = tid >> 4;
  const int m0 = blockIdx.y * BM;
  const int c0 = blockIdx.x * BN;
  const int lr = tid >> 2;
  const int lk = (tid & 3) << 2;
  float accR[4][4] = {}, accZ[4][4] = {}, accIN[4][4] = {}, accHN[4][4] = {};

  for (int seg = 0; seg <= NSEGI; ++seg) {
    const bool hseg = (seg == NSEGI);
    const float* A  = hseg ? hprev : ((seg == 0) ? A0 : (seg == 1) ? A1 : A2);
    const float* Wb = hseg ? Whh : Wih;
    const int ldw   = hseg ? Hn : ldwih;
    const int coloff = hseg ? 0 : seg * Hn;
    const float* ap = A + (size_t)(m0 + lr) * Hn + lk;
    const float* wr = Wb + (size_t)(c0 + lr) * ldw + coloff + lk;
    const float* wz = wr + (size_t)Hn * ldw;
    const float* wn = wz + (size_t)Hn * ldw;
    for (int k0 = 0; k0 < Hn; k0 += BK) {
      const float4 av = *(const float4*)(ap + k0);
      const float4 rv = *(const float4*)(wr + k0);
      const float4 zv = *(const float4*)(wz + k0);
      const float4 nv = *(const float4*)(wn + k0);
      __syncthreads();
      As[lk + 0][lr] = av.x; As[lk + 1][lr] = av.y; As[lk + 2][lr] = av.z; As[lk + 3][lr] = av.w;
      Rs[lk + 0][lr] = rv.x; Rs[lk + 1][lr] = rv.y; Rs[lk + 2][lr] = rv.z; Rs[lk + 3][lr] = rv.w;
      Zs[lk + 0][lr] = zv.x; Zs[lk + 1][lr] = zv.y; Zs[lk + 2][lr] = zv.z; Zs[lk + 3][lr] = zv.w;
      Ns[lk + 0][lr] = nv.x; Ns[lk + 1][lr] = nv.y; Ns[lk + 2][lr] = nv.z; Ns[lk + 3][lr] = nv.w;
      __syncthreads();
      #pragma unroll
      for (int kk = 0; kk < BK; ++kk) {
        const float4 a4 = *(const float4*)&As[kk][ty << 2];
        const float4 r4 = *(const float4*)&Rs[kk][tx << 2];
        const float4 z4 = *(const float4*)&Zs[kk][tx << 2];
        const float4 n4 = *(const float4*)&Ns[kk][tx << 2];
        const float aa[4] = {a4.x, a4.y, a4.z, a4.w};
        const float rr[4] = {r4.x, r4.y, r4.z, r4.w};
        const float zz[4] = {z4.x, z4.y, z4.z, z4.w};
        const float nn[4] = {n4.x, n4.y, n4.z, n4.w};
        #pragma unroll
        for (int i = 0; i < 4; ++i) {
          #pragma unroll
          for (int j = 0; j < 4; ++j) {
            accR[i][j] = fmaf(aa[i], rr[j], accR[i][j]);
            accZ[i][j] = fmaf(aa[i], zz[j], accZ[i][j]);
            if (hseg) accHN[i][j] = fmaf(aa[i], nn[j], accHN[i][j]);
            else      accIN[i][j] = fmaf(aa[i], nn[j], accIN[i][j]);
          }
        }
      }
    }
  }

  const int c = c0 + (tx << 2);
  const float4 biR = *(const float4*)&bih[c];
  const float4 bhR = *(const float4*)&bhh[c];
  const float4 biZ = *(const float4*)&bih[Hn + c];
  const float4 bhZ = *(const float4*)&bhh[Hn + c];
  const float4 biN = *(const float4*)&bih[2 * Hn + c];
  const float4 bhN = *(const float4*)&bhh[2 * Hn + c];
  const float bR[4]  = {biR.x + bhR.x, biR.y + bhR.y, biR.z + bhR.z, biR.w + bhR.w};
  const float bZ[4]  = {biZ.x + bhZ.x, biZ.y + bhZ.y, biZ.z + bhZ.z, biZ.w + bhZ.w};
  const float bIN[4] = {biN.x, biN.y, biN.z, biN.w};
  const float bHN[4] = {bhN.x, bhN.y, bhN.z, bhN.w};
  #pragma unroll
  for (int i = 0; i < 4; ++i) {
    const int m = m0 + (ty << 2) + i;
    const float4 h4 = *(const float4*)(hprev + (size_t)m * Hn + c);
    const float hh[4] = {h4.x, h4.y, h4.z, h4.w};
    float o[4];
    #pragma unroll
    for (int j = 0; j < 4; ++j) {
      const float r  = sigmf(accR[i][j] + bR[j]);
      const float z  = sigmf(accZ[i][j] + bZ[j]);
      const float nv = tanhf(accIN[i][j] + bIN[j] + r * (accHN[i][j] + bHN[j]));
      o[j] = (1.0f - z) * nv + z * hh[j];
    }
    float4 o4 = {o[0], o[1], o[2], o[3]};
    *(float4*)(hnew + (size_t)m * Hn + c) = o4;
  }
}

// Two N=64 heads (mean + softplus-std) from a [B,512] input, fused epilogues.
// MODE 0: store mean->o0, std->o1 (prior stats)
// MODE 1: f = eps*std+mean -> o0, f_kld partial -> atomicAdd(kacc)
// MODE 2: z = eps*std+mean -> o0, z_kld vs (pm_in, ps_in) -> atomicAdd(kacc)
template <int MODE>
__global__ __launch_bounds__(256)
void stat2(const float* __restrict__ Ain,
           const float* __restrict__ Wm, const float* __restrict__ bm,
           const float* __restrict__ Ws, const float* __restrict__ bs,
           const float* __restrict__ eps,
           const float* __restrict__ pm_in, const float* __restrict__ ps_in,
           float* __restrict__ o0, float* __restrict__ o1,
           float* __restrict__ kacc)
{
  __shared__ alignas(16) float As[BK][BM];
  __shared__ alignas(16) float Ms[BK][BM];
  __shared__ alignas(16) float Ss[BK][BM];
  const int tid = threadIdx.x;
  const int tx = tid & 15;
  const int ty = tid >> 4;
  const int m0 = blockIdx.x * BM;
  const int lr = tid >> 2;
  const int lk = (tid & 3) << 2;
  float accm[4][4] = {}, accs[4][4] = {};
  const float* ap = Ain + (size_t)(m0 + lr) * Hn + lk;
  const float* mp = Wm + (size_t)lr * Hn + lk;
  const float* spp = Ws + (size_t)lr * Hn + lk;
  for (int k0 = 0; k0 < Hn; k0 += BK) {
    const float4 av = *(const float4*)(ap + k0);
    const float4 mv = *(const float4*)(mp + k0);
    const float4 sv = *(const float4*)(spp + k0);
    __syncthreads();
    As[lk + 0][lr] = av.x; As[lk + 1][lr] = av.y; As[lk + 2][lr] = av.z; As[lk + 3][lr] = av.w;
    Ms[lk + 0][lr] = mv.x; Ms[lk + 1][lr] = mv.y; Ms[lk + 2][lr] = mv.z; Ms[lk + 3][lr] = mv.w;
    Ss[lk + 0][lr] = sv.x; Ss[lk + 1][lr] = sv.y; Ss[lk + 2][lr] = sv.z; Ss[lk + 3][lr] = sv.w;
    __syncthreads();
    #pragma unroll
    for (int kk = 0; kk < BK; ++kk) {
      const float4 a4 = *(const float4*)&As[kk][ty << 2];
      const float4 m4 = *(const float4*)&Ms[kk][tx << 2];
      const float4 s4 = *(const float4*)&Ss[kk][tx << 2];
      const float aa[4] = {a4.x, a4.y, a4.z, a4.w};
      const float mm[4] = {m4.x, m4.y, m4.z, m4.w};
      const float ss[4] = {s4.x, s4.y, s4.z, s4.w};
      #pragma unroll
      for (int i = 0; i < 4; ++i)
        #pragma unroll
        for (int j = 0; j < 4; ++j) {
          accm[i][j] = fmaf(aa[i], mm[j], accm[i][j]);
          accs[i][j] = fmaf(aa[i], ss[j], accs[i][j]);
        }
    }
  }
  const int c = tx << 2;
  const float4 bmv = *(const float4*)&bm[c];
  const float4 bsv = *(const float4*)&bs[c];
  const float bM[4] = {bmv.x, bmv.y, bmv.z, bmv.w};
  const float bS[4] = {bsv.x, bsv.y, bsv.z, bsv.w};
  float kld = 0.0f;
  #pragma unroll
  for (int i = 0; i < 4; ++i) {
    const int m = m0 + (ty << 2) + i;
    float mu[4], sd[4];
    #pragma unroll
    for (int j = 0; j < 4; ++j) {
      mu[j] = accm[i][j] + bM[j];
      sd[j] = splusf(accs[i][j] + bS[j]);
    }
    if (MODE == 0) {
      float4 u = {mu[0], mu[1], mu[2], mu[3]};
      float4 s = {sd[0], sd[1], sd[2], sd[3]};
      *(float4*)(o0 + (size_t)m * Zn + c) = u;
      *(float4*)(o1 + (size_t)m * Zn + c) = s;
    } else {
      const float4 e4 = *(const float4*)(eps + (size_t)m * Zn + c);
      const float ee[4] = {e4.x, e4.y, e4.z, e4.w};
      float zv[4];
      #pragma unroll
      for (int j = 0; j < 4; ++j) zv[j] = ee[j] * sd[j] + mu[j];
      float4 zz = {zv[0], zv[1], zv[2], zv[3]};
      *(float4*)(o0 + (size_t)m * Zn + c) = zz;
      if (MODE == 1) {
        #pragma unroll
        for (int j = 0; j < 4; ++j)
          kld += mu[j] * mu[j] + sd[j] * sd[j] - 2.0f * __logf(sd[j]) - 1.0f;
      } else {
        const float4 pm4 = *(const float4*)(pm_in + (size_t)m * Zn + c);
        const float4 ps4 = *(const float4*)(ps_in + (size_t)m * Zn + c);
        const float pm[4] = {pm4.x, pm4.y, pm4.z, pm4.w};
        const float ps[4] = {ps4.x, ps4.y, ps4.z, ps4.w};
        #pragma unroll
        for (int j = 0; j < 4; ++j) {
          const float dd = (mu[j] - pm[j]) / ps[j];
          const float rr = sd[j] / ps[j];
          kld += dd * dd + rr * rr - 2.0f * __logf(rr) - 1.0f;
        }
      }
    }
  }
  if (MODE != 0) {
    const float s = block_sum(kld);
    if (tid == 0) atomicAdd(kacc, 0.5f * s);
  }
}

// dec_mean GEMM (N=784) + sigmoid cross-entropy reduction (stable softplus form):
// nll += sum softplus(-a) + (1-x)*a  where a = pre-sigmoid.
__global__ __launch_bounds__(256)
void dec_nll(const float* __restrict__ dec, const float* __restrict__ dmW,
             const float* __restrict__ dmb, const float* __restrict__ xt,
             float* __restrict__ nll_acc)
{
  __shared__ alignas(16) float As[BK][BM];
  __shared__ alignas(16) float Bs[BK][BN];
  const int tid = threadIdx.x;
  const int tx = tid & 15;
  const int ty = tid >> 4;
  const int m0 = blockIdx.y * BM;
  const int n0 = blockIdx.x * BN;
  const int lr = tid >> 2;
  const int lk = (tid & 3) << 2;
  float acc[4][4] = {};
  const int wrow = (n0 + lr < Xn) ? (n0 + lr) : (Xn - 1);
  const float* ap = dec + (size_t)(m0 + lr) * Hn + lk;
  const float* wp = dmW + (size_t)wrow * Hn + lk;
  for (int k0 = 0; k0 < Hn; k0 += BK) {
    const float4 av = *(const float4*)(ap + k0);
    const float4 wv = *(const float4*)(wp + k0);
    __syncthreads();
    As[lk + 0][lr] = av.x; As[lk + 1][lr] = av.y; As[lk + 2][lr] = av.z; As[lk + 3][lr] = av.w;
    Bs[lk + 0][lr] = wv.x; Bs[lk + 1][lr] = wv.y; Bs[lk + 2][lr] = wv.z; Bs[lk + 3][lr] = wv.w;
    __syncthreads();
    #pragma unroll
    for (int kk = 0; kk < BK; ++kk) {
      const float4 a4 = *(const float4*)&As[kk][ty << 2];
      const float4 b4 = *(const float4*)&Bs[kk][tx << 2];
      const float aa[4] = {a4.x, a4.y, a4.z, a4.w};
      const float bb[4] = {b4.x, b4.y, b4.z, b4.w};
      #pragma unroll
      for (int i = 0; i < 4; ++i)
        #pragma unroll
        for (int j = 0; j < 4; ++j)
          acc[i][j] = fmaf(aa[i], bb[j], acc[i][j]);
    }
  }
  float sum = 0.0f;
  #pragma unroll
  for (int i = 0; i < 4; ++i) {
    const int m = m0 + (ty << 2) + i;
    #pragma unroll
    for (int j = 0; j < 4; ++j) {
      const int n = n0 + (tx << 2) + j;
      if (n < Xn) {
        const float a = acc[i][j] + dmb[n];
        const float xv = xt[(size_t)m * Xn + n];
        sum += splusf(-a) + (1.0f - xv) * a;
      }
    }
  }
  const float s = block_sum(sum);
  if (tid == 0) atomicAdd(nll_acc, s);
}

} // anonymous namespace

extern "C" void kernel_launch(void* const* d_in, const int* in_sizes, int n_in,
                              void* d_out, int out_size, void* d_ws, size_t ws_size,
                              hipStream_t stream)
{
  (void)in_sizes; (void)n_in; (void)out_size;
  const float* x     = (const float*)d_in[0];
  const float* eps_f = (const float*)d_in[1];
  const float* eps_z = (const float*)d_in[2];
  const float* pxW1  = (const float*)d_in[3];
  const float* pxb1  = (const float*)d_in[4];
  const float* pxW2  = (const float*)d_in[5];
  const float* pxb2  = (const float*)d_in[6];
  const float* pzW   = (const float*)d_in[7];
  const float* pzb   = (const float*)d_in[8];
  const float* pfW   = (const float*)d_in[9];
  const float* pfb   = (const float*)d_in[10];
  const float* rWih  = (const float*)d_in[11];
  const float* rWhh  = (const float*)d_in[12];
  const float* rbih  = (const float*)d_in[13];
  const float* rbhh  = (const float*)d_in[14];
  const float* zpW   = (const float*)d_in[15];
  const float* zpb   = (const float*)d_in[16];
  const float* zpmW  = (const float*)d_in[17];
  const float* zpmb  = (const float*)d_in[18];
  const float* zpsW  = (const float*)d_in[19];
  const float* zpsb  = (const float*)d_in[20];
  const float* feWih = (const float*)d_in[21];
  const float* feWhh = (const float*)d_in[22];
  const float* febih = (const float*)d_in[23];
  const float* febhh = (const float*)d_in[24];
  const float* femW  = (const float*)d_in[25];
  const float* femb  = (const float*)d_in[26];
  const float* fesW  = (const float*)d_in[27];
  const float* fesb  = (const float*)d_in[28];
  const float* zeW1  = (const float*)d_in[29];
  const float* zeb1  = (const float*)d_in[30];
  const float* zeW2  = (const float*)d_in[31];
  const float* zeb2  = (const float*)d_in[32];
  const float* zemW  = (const float*)d_in[33];
  const float* zemb  = (const float*)d_in[34];
  const float* zesW  = (const float*)d_in[35];
  const float* zesb  = (const float*)d_in[36];
  const float* dW1   = (const float*)d_in[37];
  const float* db1   = (const float*)d_in[38];
  const float* dW2   = (const float*)d_in[39];
  const float* db2   = (const float*)d_in[40];
  const float* dmW   = (const float*)d_in[41];
  const float* dmb   = (const float*)d_in[42];
  float* out = (float*)d_out;

  // ---- workspace carve-up ----
  const size_t smalls = (size_t)11 * Bn * Hn + (size_t)4 * Bn * Zn; // activation buffers
  const size_t availf = ws_size / sizeof(float);
  int CH = 16; // phase-A chunking along T (trade tmp size vs launches)
  while (CH > 1 && (size_t)Tn * Bn * Hn + (size_t)CH * Bn * Hn + smalls > availf) CH >>= 1;

  float* wsf = (float*)d_ws;
  size_t off = 0;
  auto alloc = [&](size_t n) { float* p = wsf + off; off += n; return p; };
  float* phi_x = alloc((size_t)Tn * Bn * Hn);
  float* tmp   = alloc((size_t)CH * Bn * Hn);
  float* fh_a  = alloc((size_t)Bn * Hn);
  float* h_a   = alloc((size_t)Bn * Hn);   // adjacent to fh_a: one memset covers both
  float* fh_b  = alloc((size_t)Bn * Hn);
  float* h_b   = alloc((size_t)Bn * Hn);
  float* fbuf  = alloc((size_t)Bn * Fn);
  float* phi_f = alloc((size_t)Bn * Hn);
  float* zp    = alloc((size_t)Bn * Hn);
  float* zpm   = alloc((size_t)Bn * Zn);
  float* zps   = alloc((size_t)Bn * Zn);
  float* zepre = alloc((size_t)Bn * Hn);
  float* ze    = alloc((size_t)Bn * Hn);
  float* zt    = alloc((size_t)Bn * Zn);
  float* phiz  = alloc((size_t)Bn * Hn);
  float* dtmp  = alloc((size_t)Bn * Hn);
  float* dec   = alloc((size_t)Bn * Hn);

  hipMemsetAsync(d_out, 0, 3 * sizeof(float), stream);
  hipMemsetAsync(fh_a, 0, 2 * (size_t)Bn * Hn * sizeof(float), stream); // fh_a + h_a

  const dim3 blk(256);
  const dim3 gBH(Hn / BN, Bn / BM);         // [512x512] output tiles

  // ---- Phase A: phi_x = relu(relu(x@pxW1^T+b)@pxW2^T+b) over all T ----
  for (int c = 0; c < Tn / CH; ++c) {
    const dim3 gA(Hn / BN, CH * Bn / BM);
    gemm_nt<1, true><<<gA, blk, 0, stream>>>(
        x + (size_t)c * CH * Bn * Xn, pxW1, Xn, Xn,
        nullptr, nullptr, 0, 0, nullptr, nullptr, 0, 0,
        pxb1, tmp, Hn);
    gemm_nt<1, true><<<gA, blk, 0, stream>>>(
        tmp, pxW2, Hn, Hn,
        nullptr, nullptr, 0, 0, nullptr, nullptr, 0, 0,
        pxb2, phi_x + (size_t)c * CH * Bn * Hn, Hn);
  }

  // ---- Phase B: f-encoder GRU over T; final hidden in fc ----
  float* fc = fh_a;
  float* fn = fh_b;
  for (int t = 0; t < Tn; ++t) {
    gru_step<1><<<gBH, blk, 0, stream>>>(
        phi_x + (size_t)t * Bn * Hn, nullptr, nullptr,
        feWih, Hn, fc, feWhh, febih, febhh, fn);
    float* sw = fc; fc = fn; fn = sw;
  }

  // ---- Phase C: f stats, f sample, f_kld, phi_f ----
  stat2<1><<<dim3(Bn / BM), blk, 0, stream>>>(
      fc, femW, femb, fesW, fesb, eps_f, nullptr, nullptr, fbuf, nullptr, out + 0);
  gemm_nt<1, true><<<gBH, blk, 0, stream>>>(
      fbuf, pfW, Fn, Fn,
      nullptr, nullptr, 0, 0, nullptr, nullptr, 0, 0,
      pfb, phi_f, Hn);

  // ---- Phase D: main recurrence ----
  float* hc = h_a;
  float* hb = h_b;
  for (int t = 0; t < Tn; ++t) {
    const float* px_t = phi_x + (size_t)t * Bn * Hn;
    // prior path
    gemm_nt<1, true><<<gBH, blk, 0, stream>>>(
        hc, zpW, Hn, Hn, nullptr, nullptr, 0, 0, nullptr, nullptr, 0, 0,
        zpb, zp, Hn);
    stat2<0><<<dim3(Bn / BM), blk, 0, stream>>>(
        zp, zpmW, zpmb, zpsW, zpsb, nullptr, nullptr, nullptr, zpm, zps, nullptr);
    // encoder path (concat(px_t, h) via 2 segments)
    gemm_nt<2, true><<<gBH, blk, 0, stream>>>(
        px_t, zeW1, 2 * Hn, Hn,
        hc, zeW1 + Hn, 2 * Hn, Hn,
        nullptr, nullptr, 0, 0,
        zeb1, zepre, Hn);
    gemm_nt<1, true><<<gBH, blk, 0, stream>>>(
        zepre, zeW2, Hn, Hn, nullptr, nullptr, 0, 0, nullptr, nullptr, 0, 0,
        zeb2, ze, Hn);
    stat2<2><<<dim3(Bn / BM), blk, 0, stream>>>(
        ze, zemW, zemb, zesW, zesb, eps_z + (size_t)t * Bn * Zn, zpm, zps,
        zt, nullptr, out + 1);
    // phi_z
    gemm_nt<1, true><<<gBH, blk, 0, stream>>>(
        zt, pzW, Zn, Zn, nullptr, nullptr, 0, 0, nullptr, nullptr, 0, 0,
        pzb, phiz, Hn);
    // decoder (concat(phi_z, phi_f, h) via 3 segments)
    gemm_nt<3, true><<<gBH, blk, 0, stream>>>(
        phiz, dW1, 3 * Hn, Hn,
        phi_f, dW1 + Hn, 3 * Hn, Hn,
        hc, dW1 + 2 * Hn, 3 * Hn, Hn,
        db1, dtmp, Hn);
    gemm_nt<1, true><<<gBH, blk, 0, stream>>>(
        dtmp, dW2, Hn, Hn, nullptr, nullptr, 0, 0, nullptr, nullptr, 0, 0,
        db2, dec, Hn);
    dec_nll<<<dim3((Xn + BN - 1) / BN, Bn / BM), blk, 0, stream>>>(
        dec, dmW, dmb, x + (size_t)t * Bn * Xn, out + 2);
    // recurrent GRU (concat(px_t, phi_z, phi_f) via 3 i-segments)
    gru_step<3><<<gBH, blk, 0, stream>>>(
        px_t, phiz, phi_f,
        rWih, 3 * Hn, hc, rWhh, rbih, rbhh, hb);
    float* sw = hc; hc = hb; hb = sw;
  }
}

// Round 2
// 12684.431 us; speedup vs baseline: 6.5837x; 6.5837x over previous
//
#include <hip/hip_runtime.h>
#include <cmath>

namespace {

constexpr int Tn = 64;
constexpr int Bn = 512;
constexpr int Xn = 784;
constexpr int XnP = 800;   // Xn padded to %32 for MFMA K-loop
constexpr int Fn = 64;
constexpr int Zn = 64;
constexpr int Hn = 512;

typedef __attribute__((ext_vector_type(8))) short bf16x8;
typedef __attribute__((ext_vector_type(4))) float f32x4;

__device__ __forceinline__ unsigned short f2b(float v) {
  unsigned int u = __float_as_uint(v);
  unsigned int r = (u + 0x7FFFu + ((u >> 16) & 1u)) >> 16;
  return (unsigned short)r;
}
__device__ __forceinline__ float b2f(unsigned short u) {
  return __uint_as_float(((unsigned int)u) << 16);
}
__device__ __forceinline__ float sigmf(float v) { return 1.0f / (1.0f + __expf(-v)); }
__device__ __forceinline__ float splusf(float v) {
  return v > 0.0f ? (v + log1pf(__expf(-v))) : log1pf(__expf(v));
}

__device__ __forceinline__ float block_sum(float v) {
  __shared__ float red[4];
  #pragma unroll
  for (int off = 32; off > 0; off >>= 1) v += __shfl_down(v, off, 64);
  if ((threadIdx.x & 63) == 0) red[threadIdx.x >> 6] = v;
  __syncthreads();
  float s = 0.0f;
  if (threadIdx.x == 0) s = red[0] + red[1] + red[2] + red[3];
  return s;
}

// ---- fp32 -> bf16 converters (one-time per call) ----
__global__ void cvt(const float* __restrict__ s, unsigned short* __restrict__ d, int n) {
  int i = blockIdx.x * 256 + threadIdx.x;
  if (i < n) d[i] = f2b(s[i]);
}
// [R][C] -> [R][Cp], zero-fill columns C..Cp
__global__ void cvt_pad(const float* __restrict__ s, unsigned short* __restrict__ d,
                        int C, int Cp, int n) {
  int i = blockIdx.x * 256 + threadIdx.x;
  if (i < n) {
    int r = i / Cp, c = i - r * Cp;
    d[i] = (c < C) ? f2b(s[(size_t)r * C + c]) : (unsigned short)0;
  }
}

// ---- bf16 MFMA GEMM: C = act( sum_seg A_seg . W_seg^T + bias ) ----
// 64x64 tile/block, 256 thr (4 waves), wave w = rows [16w,16w+16) x 4 col-tiles.
template <int NSEG, bool RELU>
__global__ __launch_bounds__(256)
void gemm_bf16(const unsigned short* __restrict__ A0, const unsigned short* __restrict__ W0, int ldw0, int K0,
               const unsigned short* __restrict__ A1, const unsigned short* __restrict__ W1, int ldw1, int K1,
               const unsigned short* __restrict__ A2, const unsigned short* __restrict__ W2, int ldw2, int K2,
               const float* __restrict__ bias, unsigned short* __restrict__ C, int ldc)
{
  __shared__ alignas(16) unsigned short As[64][40];
  __shared__ alignas(16) unsigned short Bs[64][40];
  const int tid = threadIdx.x;
  const int m0 = blockIdx.y * 64, n0 = blockIdx.x * 64;
  const int srow = tid >> 2, scb = (tid & 3) * 8;
  const int lane = tid & 63, w = tid >> 6, l15 = lane & 15, q = lane >> 4;
  f32x4 acc[4];
  #pragma unroll
  for (int j = 0; j < 4; ++j) acc[j] = (f32x4){0.f, 0.f, 0.f, 0.f};

  for (int seg = 0; seg < NSEG; ++seg) {
    const unsigned short* A = (seg == 0) ? A0 : (seg == 1) ? A1 : A2;
    const unsigned short* W = (seg == 0) ? W0 : (seg == 1) ? W1 : W2;
    const int ldw = (seg == 0) ? ldw0 : (seg == 1) ? ldw1 : ldw2;
    const int K   = (seg == 0) ? K0 : (seg == 1) ? K1 : K2;
    const unsigned short* ap = A + (size_t)(m0 + srow) * K + scb;
    const unsigned short* wp = W + (size_t)(n0 + srow) * ldw + scb;
    for (int k0 = 0; k0 < K; k0 += 32) {
      const uint4 av = *(const uint4*)(ap + k0);
      const uint4 wv = *(const uint4*)(wp + k0);
      __syncthreads();
      *(uint4*)&As[srow][scb] = av;
      *(uint4*)&Bs[srow][scb] = wv;
      __syncthreads();
      const bf16x8 a = *(const bf16x8*)&As[w * 16 + l15][q * 8];
      #pragma unroll
      for (int j = 0; j < 4; ++j) {
        const bf16x8 b = *(const bf16x8*)&Bs[j * 16 + l15][q * 8];
        acc[j] = __builtin_amdgcn_mfma_f32_16x16x32_bf16(a, b, acc[j], 0, 0, 0);
      }
    }
  }

  #pragma unroll
  for (int j = 0; j < 4; ++j) {
    const int col = n0 + j * 16 + l15;
    const float bv = bias[col];
    #pragma unroll
    for (int r = 0; r < 4; ++r) {
      const int row = m0 + w * 16 + q * 4 + r;
      float v = acc[j][r] + bv;
      if (RELU) v = fmaxf(v, 0.0f);
      C[(size_t)row * ldc + col] = f2b(v);
    }
  }
}

// ---- fused GRU step, bf16 MFMA ----
template <int NSEGI>
__global__ __launch_bounds__(256)
void gru_bf16(const unsigned short* __restrict__ A0, const unsigned short* __restrict__ A1,
              const unsigned short* __restrict__ A2,
              const unsigned short* __restrict__ Wih, int ldwih,
              const unsigned short* __restrict__ hprev, const unsigned short* __restrict__ Whh,
              const float* __restrict__ bih, const float* __restrict__ bhh,
              unsigned short* __restrict__ hnew)
{
  __shared__ alignas(16) unsigned short As[64][40];
  __shared__ alignas(16) unsigned short Rs[64][40];
  __shared__ alignas(16) unsigned short Zs[64][40];
  __shared__ alignas(16) unsigned short Ns[64][40];
  const int tid = threadIdx.x;
  const int m0 = blockIdx.y * 64, c0 = blockIdx.x * 64;
  const int srow = tid >> 2, scb = (tid & 3) * 8;
  const int lane = tid & 63, w = tid >> 6, l15 = lane & 15, q = lane >> 4;
  f32x4 aR[4], aZ[4], aI[4], aH[4];
  #pragma unroll
  for (int j = 0; j < 4; ++j) {
    aR[j] = (f32x4){0.f, 0.f, 0.f, 0.f}; aZ[j] = aR[j]; aI[j] = aR[j]; aH[j] = aR[j];
  }

  for (int seg = 0; seg <= NSEGI; ++seg) {
    const bool hseg = (seg == NSEGI);
    const unsigned short* A  = hseg ? hprev : ((seg == 0) ? A0 : (seg == 1) ? A1 : A2);
    const unsigned short* Wb = hseg ? Whh : Wih;
    const int ldw  = hseg ? Hn : ldwih;
    const int coff = hseg ? 0 : seg * Hn;
    const unsigned short* ap = A + (size_t)(m0 + srow) * Hn + scb;
    const unsigned short* wr = Wb + (size_t)(c0 + srow) * ldw + coff + scb;
    const unsigned short* wz = wr + (size_t)Hn * ldw;
    const unsigned short* wn = wz + (size_t)Hn * ldw;
    for (int k0 = 0; k0 < Hn; k0 += 32) {
      const uint4 av = *(const uint4*)(ap + k0);
      const uint4 rv = *(const uint4*)(wr + k0);
      const uint4 zv = *(const uint4*)(wz + k0);
      const uint4 nv = *(const uint4*)(wn + k0);
      __syncthreads();
      *(uint4*)&As[srow][scb] = av;
      *(uint4*)&Rs[srow][scb] = rv;
      *(uint4*)&Zs[srow][scb] = zv;
      *(uint4*)&Ns[srow][scb] = nv;
      __syncthreads();
      const bf16x8 a = *(const bf16x8*)&As[w * 16 + l15][q * 8];
      #pragma unroll
      for (int j = 0; j < 4; ++j) {
        const bf16x8 br = *(const bf16x8*)&Rs[j * 16 + l15][q * 8];
        const bf16x8 bz = *(const bf16x8*)&Zs[j * 16 + l15][q * 8];
        const bf16x8 bn = *(const bf16x8*)&Ns[j * 16 + l15][q * 8];
        aR[j] = __builtin_amdgcn_mfma_f32_16x16x32_bf16(a, br, aR[j], 0, 0, 0);
        aZ[j] = __builtin_amdgcn_mfma_f32_16x16x32_bf16(a, bz, aZ[j], 0, 0, 0);
        if (hseg) aH[j] = __builtin_amdgcn_mfma_f32_16x16x32_bf16(a, bn, aH[j], 0, 0, 0);
        else      aI[j] = __builtin_amdgcn_mfma_f32_16x16x32_bf16(a, bn, aI[j], 0, 0, 0);
      }
    }
  }

  #pragma unroll
  for (int j = 0; j < 4; ++j) {
    const int c = c0 + j * 16 + l15;
    const float bR = bih[c] + bhh[c];
    const float bZ = bih[Hn + c] + bhh[Hn + c];
    const float bI = bih[2 * Hn + c];
    const float bH = bhh[2 * Hn + c];
    #pragma unroll
    for (int r = 0; r < 4; ++r) {
      const int m = m0 + w * 16 + q * 4 + r;
      const float h = b2f(hprev[(size_t)m * Hn + c]);
      const float rg = sigmf(aR[j][r] + bR);
      const float zg = sigmf(aZ[j][r] + bZ);
      const float ng = tanhf(aI[j][r] + bI + rg * (aH[j][r] + bH));
      hnew[(size_t)m * Hn + c] = f2b((1.0f - zg) * ng + zg * h);
    }
  }
}

// ---- two N=64 heads (mean + softplus std), fused sample/KLD ----
// MODE 0: store mean->o0m, std->o1s (fp32). MODE 1: f=eps*sd+mu -> o0b, f_kld.
// MODE 2: z=eps*sd+mu -> o0b, z_kld vs (pm,ps).
template <int MODE>
__global__ __launch_bounds__(256)
void stat2_bf16(const unsigned short* __restrict__ Ain,
                const unsigned short* __restrict__ Wm, const float* __restrict__ bm,
                const unsigned short* __restrict__ Ws, const float* __restrict__ bs,
                const float* __restrict__ eps,
                const float* __restrict__ pm_in, const float* __restrict__ ps_in,
                unsigned short* __restrict__ o0b, float* __restrict__ o0m,
                float* __restrict__ o1s, float* __restrict__ kacc)
{
  __shared__ alignas(16) unsigned short As[64][40];
  __shared__ alignas(16) unsigned short Ms[64][40];
  __shared__ alignas(16) unsigned short Ss[64][40];
  const int tid = threadIdx.x;
  const int m0 = blockIdx.x * 64;
  const int srow = tid >> 2, scb = (tid & 3) * 8;
  const int lane = tid & 63, w = tid >> 6, l15 = lane & 15, q = lane >> 4;
  f32x4 am[4], as_[4];
  #pragma unroll
  for (int j = 0; j < 4; ++j) { am[j] = (f32x4){0.f, 0.f, 0.f, 0.f}; as_[j] = am[j]; }

  const unsigned short* ap = Ain + (size_t)(m0 + srow) * Hn + scb;
  const unsigned short* mp = Wm + (size_t)srow * Hn + scb;
  const unsigned short* sp = Ws + (size_t)srow * Hn + scb;
  for (int k0 = 0; k0 < Hn; k0 += 32) {
    const uint4 av = *(const uint4*)(ap + k0);
    const uint4 mv = *(const uint4*)(mp + k0);
    const uint4 sv = *(const uint4*)(sp + k0);
    __syncthreads();
    *(uint4*)&As[srow][scb] = av;
    *(uint4*)&Ms[srow][scb] = mv;
    *(uint4*)&Ss[srow][scb] = sv;
    __syncthreads();
    const bf16x8 a = *(const bf16x8*)&As[w * 16 + l15][q * 8];
    #pragma unroll
    for (int j = 0; j < 4; ++j) {
      const bf16x8 bm8 = *(const bf16x8*)&Ms[j * 16 + l15][q * 8];
      const bf16x8 bs8 = *(const bf16x8*)&Ss[j * 16 + l15][q * 8];
      am[j]  = __builtin_amdgcn_mfma_f32_16x16x32_bf16(a, bm8, am[j], 0, 0, 0);
      as_[j] = __builtin_amdgcn_mfma_f32_16x16x32_bf16(a, bs8, as_[j], 0, 0, 0);
    }
  }

  float kld = 0.0f;
  #pragma unroll
  for (int j = 0; j < 4; ++j) {
    const int c = j * 16 + l15;
    const float bmv = bm[c], bsv = bs[c];
    #pragma unroll
    for (int r = 0; r < 4; ++r) {
      const int m = m0 + w * 16 + q * 4 + r;
      const float mu = am[j][r] + bmv;
      const float sd = splusf(as_[j][r] + bsv);
      if (MODE == 0) {
        o0m[(size_t)m * Zn + c] = mu;
        o1s[(size_t)m * Zn + c] = sd;
      } else {
        const float e = eps[(size_t)m * Zn + c];
        o0b[(size_t)m * Zn + c] = f2b(e * sd + mu);
        if (MODE == 1) {
          kld += mu * mu + sd * sd - 2.0f * __logf(sd) - 1.0f;
        } else {
          const float pm = pm_in[(size_t)m * Zn + c];
          const float ps = ps_in[(size_t)m * Zn + c];
          const float dd = (mu - pm) / ps;
          const float rr = sd / ps;
          kld += dd * dd + rr * rr - 2.0f * __logf(rr) - 1.0f;
        }
      }
    }
  }
  if (MODE != 0) {
    const float s = block_sum(kld);
    if (tid == 0) atomicAdd(kacc, 0.5f * s);
  }
}

// ---- decoder mean GEMM (N=784) + fused stable BCE reduction ----
__global__ __launch_bounds__(256)
void dec_nll_bf16(const unsigned short* __restrict__ dec, const unsigned short* __restrict__ dmW,
                  const float* __restrict__ dmb, const float* __restrict__ xt,
                  float* __restrict__ nll)
{
  __shared__ alignas(16) unsigned short As[64][40];
  __shared__ alignas(16) unsigned short Bs[64][40];
  const int tid = threadIdx.x;
  const int m0 = blockIdx.y * 64, n0 = blockIdx.x * 64;
  const int srow = tid >> 2, scb = (tid & 3) * 8;
  const int lane = tid & 63, w = tid >> 6, l15 = lane & 15, q = lane >> 4;
  f32x4 acc[4];
  #pragma unroll
  for (int j = 0; j < 4; ++j) acc[j] = (f32x4){0.f, 0.f, 0.f, 0.f};

  const int wrow = (n0 + srow < Xn) ? (n0 + srow) : (Xn - 1);
  const unsigned short* ap = dec + (size_t)(m0 + srow) * Hn + scb;
  const unsigned short* wp = dmW + (size_t)wrow * Hn + scb;
  for (int k0 = 0; k0 < Hn; k0 += 32) {
    const uint4 av = *(const uint4*)(ap + k0);
    const uint4 wv = *(const uint4*)(wp + k0);
    __syncthreads();
    *(uint4*)&As[srow][scb] = av;
    *(uint4*)&Bs[srow][scb] = wv;
    __syncthreads();
    const bf16x8 a = *(const bf16x8*)&As[w * 16 + l15][q * 8];
    #pragma unroll
    for (int j = 0; j < 4; ++j) {
      const bf16x8 b = *(const bf16x8*)&Bs[j * 16 + l15][q * 8];
      acc[j] = __builtin_amdgcn_mfma_f32_16x16x32_bf16(a, b, acc[j], 0, 0, 0);
    }
  }

  float sum = 0.0f;
  #pragma unroll
  for (int j = 0; j < 4; ++j) {
    const int n = n0 + j * 16 + l15;
    if (n < Xn) {
      const float bv = dmb[n];
      #pragma unroll
      for (int r = 0; r < 4; ++r) {
        const int m = m0 + w * 16 + q * 4 + r;
        const float a = acc[j][r] + bv;
        const float xv = xt[(size_t)m * Xn + n];
        sum += splusf(-a) + (1.0f - xv) * a;
      }
    }
  }
  const float s = block_sum(sum);
  if (tid == 0) atomicAdd(nll, s);
}

} // anonymous namespace

extern "C" void kernel_launch(void* const* d_in, const int* in_sizes, int n_in,
                              void* d_out, int out_size, void* d_ws, size_t ws_size,
                              hipStream_t stream)
{
  (void)in_sizes; (void)n_in; (void)out_size;
  const float* x     = (const float*)d_in[0];
  const float* eps_f = (const float*)d_in[1];
  const float* eps_z = (const float*)d_in[2];
  const float* pxW1  = (const float*)d_in[3];
  const float* pxb1  = (const float*)d_in[4];
  const float* pxW2  = (const float*)d_in[5];
  const float* pxb2  = (const float*)d_in[6];
  const float* pzW   = (const float*)d_in[7];
  const float* pzb   = (const float*)d_in[8];
  const float* pfW   = (const float*)d_in[9];
  const float* pfb   = (const float*)d_in[10];
  const float* rWih  = (const float*)d_in[11];
  const float* rWhh  = (const float*)d_in[12];
  const float* rbih  = (const float*)d_in[13];
  const float* rbhh  = (const float*)d_in[14];
  const float* zpW   = (const float*)d_in[15];
  const float* zpb   = (const float*)d_in[16];
  const float* zpmW  = (const float*)d_in[17];
  const float* zpmb  = (const float*)d_in[18];
  const float* zpsW  = (const float*)d_in[19];
  const float* zpsb  = (const float*)d_in[20];
  const float* feWih = (const float*)d_in[21];
  const float* feWhh = (const float*)d_in[22];
  const float* febih = (const float*)d_in[23];
  const float* febhh = (const float*)d_in[24];
  const float* femW  = (const float*)d_in[25];
  const float* femb  = (const float*)d_in[26];
  const float* fesW  = (const float*)d_in[27];
  const float* fesb  = (const float*)d_in[28];
  const float* zeW1  = (const float*)d_in[29];
  const float* zeb1  = (const float*)d_in[30];
  const float* zeW2  = (const float*)d_in[31];
  const float* zeb2  = (const float*)d_in[32];
  const float* zemW  = (const float*)d_in[33];
  const float* zemb  = (const float*)d_in[34];
  const float* zesW  = (const float*)d_in[35];
  const float* zesb  = (const float*)d_in[36];
  const float* dW1   = (const float*)d_in[37];
  const float* db1   = (const float*)d_in[38];
  const float* dW2   = (const float*)d_in[39];
  const float* db2   = (const float*)d_in[40];
  const float* dmW   = (const float*)d_in[41];
  const float* dmb   = (const float*)d_in[42];
  float* out = (float*)d_out;

  // ---- byte allocator over d_ws ----
  char* base = (char*)d_ws;
  size_t off = 0;
  auto ab = [&](size_t bytes) -> void* {
    void* p = base + off;
    off += (bytes + 255) & ~(size_t)255;
    return p;
  };
  typedef unsigned short us;

  // bf16 weights
  us* b_pxW1  = (us*)ab((size_t)512 * XnP * 2);
  us* b_pxW2  = (us*)ab((size_t)512 * 512 * 2);
  us* b_pzW   = (us*)ab((size_t)512 * 64 * 2);
  us* b_pfW   = (us*)ab((size_t)512 * 64 * 2);
  us* b_rWih  = (us*)ab((size_t)1536 * 1536 * 2);
  us* b_rWhh  = (us*)ab((size_t)1536 * 512 * 2);
  us* b_zpW   = (us*)ab((size_t)512 * 512 * 2);
  us* b_zpmW  = (us*)ab((size_t)64 * 512 * 2);
  us* b_zpsW  = (us*)ab((size_t)64 * 512 * 2);
  us* b_feWih = (us*)ab((size_t)1536 * 512 * 2);
  us* b_feWhh = (us*)ab((size_t)1536 * 512 * 2);
  us* b_femW  = (us*)ab((size_t)64 * 512 * 2);
  us* b_fesW  = (us*)ab((size_t)64 * 512 * 2);
  us* b_zeW1  = (us*)ab((size_t)512 * 1024 * 2);
  us* b_zeW2  = (us*)ab((size_t)512 * 512 * 2);
  us* b_zemW  = (us*)ab((size_t)64 * 512 * 2);
  us* b_zesW  = (us*)ab((size_t)64 * 512 * 2);
  us* b_dW1   = (us*)ab((size_t)512 * 1536 * 2);
  us* b_dW2   = (us*)ab((size_t)512 * 512 * 2);
  us* b_dmW   = (us*)ab((size_t)Xn * 512 * 2);

  // bf16 activations
  us* phi_x = (us*)ab((size_t)Tn * Bn * Hn * 2);
  us* fh_a  = (us*)ab((size_t)Bn * Hn * 2);
  us* h_a   = (us*)ab((size_t)Bn * Hn * 2);   // adjacent to fh_a (one memset)
  us* fh_b  = (us*)ab((size_t)Bn * Hn * 2);
  us* h_b   = (us*)ab((size_t)Bn * Hn * 2);
  us* fbuf  = (us*)ab((size_t)Bn * Fn * 2);
  us* phi_f = (us*)ab((size_t)Bn * Hn * 2);
  us* zp    = (us*)ab((size_t)Bn * Hn * 2);
  us* zepre = (us*)ab((size_t)Bn * Hn * 2);
  us* ze    = (us*)ab((size_t)Bn * Hn * 2);
  us* zt    = (us*)ab((size_t)Bn * Zn * 2);
  us* phiz  = (us*)ab((size_t)Bn * Hn * 2);
  us* dtmp  = (us*)ab((size_t)Bn * Hn * 2);
  us* dec   = (us*)ab((size_t)Bn * Hn * 2);
  float* zpm = (float*)ab((size_t)Bn * Zn * 4);
  float* zps = (float*)ab((size_t)Bn * Zn * 4);

  // adaptive phase-A chunking (x-convert + tmp buffers)
  int CH = 16;
  while (CH > 1 && off + (size_t)CH * (Bn * XnP + Bn * Hn) * 2 + 4096 > ws_size) CH >>= 1;
  us* xch  = (us*)ab((size_t)CH * Bn * XnP * 2);
  us* tmpb = (us*)ab((size_t)CH * Bn * Hn * 2);

  hipMemsetAsync(d_out, 0, 3 * sizeof(float), stream);
  hipMemsetAsync(fh_a, 0, 2 * (size_t)Bn * Hn * 2, stream);  // fh_a + h_a

  const dim3 blk(256);
  auto CVT = [&](const float* s, us* d, size_t n) {
    cvt<<<dim3((unsigned)((n + 255) / 256)), blk, 0, stream>>>(s, d, (int)n);
  };

  // ---- weight conversion (one pass) ----
  {
    const size_t n = (size_t)512 * XnP;
    cvt_pad<<<dim3((unsigned)((n + 255) / 256)), blk, 0, stream>>>(pxW1, b_pxW1, Xn, XnP, (int)n);
  }
  CVT(pxW2, b_pxW2, (size_t)512 * 512);
  CVT(pzW, b_pzW, (size_t)512 * 64);
  CVT(pfW, b_pfW, (size_t)512 * 64);
  CVT(rWih, b_rWih, (size_t)1536 * 1536);
  CVT(rWhh, b_rWhh, (size_t)1536 * 512);
  CVT(zpW, b_zpW, (size_t)512 * 512);
  CVT(zpmW, b_zpmW, (size_t)64 * 512);
  CVT(zpsW, b_zpsW, (size_t)64 * 512);
  CVT(feWih, b_feWih, (size_t)1536 * 512);
  CVT(feWhh, b_feWhh, (size_t)1536 * 512);
  CVT(femW, b_femW, (size_t)64 * 512);
  CVT(fesW, b_fesW, (size_t)64 * 512);
  CVT(zeW1, b_zeW1, (size_t)512 * 1024);
  CVT(zeW2, b_zeW2, (size_t)512 * 512);
  CVT(zemW, b_zemW, (size_t)64 * 512);
  CVT(zesW, b_zesW, (size_t)64 * 512);
  CVT(dW1, b_dW1, (size_t)512 * 1536);
  CVT(dW2, b_dW2, (size_t)512 * 512);
  CVT(dmW, b_dmW, (size_t)Xn * 512);

  const dim3 gBH(Hn / 64, Bn / 64);  // (8,8)

  // ---- Phase A: phi_x ----
  for (int c = 0; c < Tn / CH; ++c) {
    const size_t nx = (size_t)CH * Bn * XnP;
    cvt_pad<<<dim3((unsigned)((nx + 255) / 256)), blk, 0, stream>>>(
        x + (size_t)c * CH * Bn * Xn, xch, Xn, XnP, (int)nx);
    const dim3 gA(Hn / 64, CH * Bn / 64);
    gemm_bf16<1, true><<<gA, blk, 0, stream>>>(
        xch, b_pxW1, XnP, XnP, nullptr, nullptr, 0, 0, nullptr, nullptr, 0, 0,
        pxb1, tmpb, Hn);
    gemm_bf16<1, true><<<gA, blk, 0, stream>>>(
        tmpb, b_pxW2, Hn, Hn, nullptr, nullptr, 0, 0, nullptr, nullptr, 0, 0,
        pxb2, phi_x + (size_t)c * CH * Bn * Hn, Hn);
  }

  // ---- Phase B: f-encoder GRU ----
  us* fc = fh_a; us* fn = fh_b;
  for (int t = 0; t < Tn; ++t) {
    gru_bf16<1><<<gBH, blk, 0, stream>>>(
        phi_x + (size_t)t * Bn * Hn, nullptr, nullptr,
        b_feWih, Hn, fc, b_feWhh, febih, febhh, fn);
    us* sw = fc; fc = fn; fn = sw;
  }

  // ---- Phase C: f stats + phi_f ----
  stat2_bf16<1><<<dim3(Bn / 64), blk, 0, stream>>>(
      fc, b_femW, femb, b_fesW, fesb, eps_f, nullptr, nullptr,
      fbuf, nullptr, nullptr, out + 0);
  gemm_bf16<1, true><<<gBH, blk, 0, stream>>>(
      fbuf, b_pfW, Fn, Fn, nullptr, nullptr, 0, 0, nullptr, nullptr, 0, 0,
      pfb, phi_f, Hn);

  // ---- Phase D: main recurrence ----
  us* hc = h_a; us* hb = h_b;
  for (int t = 0; t < Tn; ++t) {
    const us* px_t = phi_x + (size_t)t * Bn * Hn;
    gemm_bf16<1, true><<<gBH, blk, 0, stream>>>(
        hc, b_zpW, Hn, Hn, nullptr, nullptr, 0, 0, nullptr, nullptr, 0, 0,
        zpb, zp, Hn);
    stat2_bf16<0><<<dim3(Bn / 64), blk, 0, stream>>>(
        zp, b_zpmW, zpmb, b_zpsW, zpsb, nullptr, nullptr, nullptr,
        nullptr, zpm, zps, nullptr);
    gemm_bf16<2, true><<<gBH, blk, 0, stream>>>(
        px_t, b_zeW1, 2 * Hn, Hn,
        hc, b_zeW1 + Hn, 2 * Hn, Hn,
        nullptr, nullptr, 0, 0,
        zeb1, zepre, Hn);
    gemm_bf16<1, true><<<gBH, blk, 0, stream>>>(
        zepre, b_zeW2, Hn, Hn, nullptr, nullptr, 0, 0, nullptr, nullptr, 0, 0,
        zeb2, ze, Hn);
    stat2_bf16<2><<<dim3(Bn / 64), blk, 0, stream>>>(
        ze, b_zemW, zemb, b_zesW, zesb, eps_z + (size_t)t * Bn * Zn, zpm, zps,
        zt, nullptr, nullptr, out + 1);
    gemm_bf16<1, true><<<gBH, blk, 0, stream>>>(
        zt, b_pzW, Zn, Zn, nullptr, nullptr, 0, 0, nullptr, nullptr, 0, 0,
        pzb, phiz, Hn);
    gemm_bf16<3, true><<<gBH, blk, 0, stream>>>(
        phiz, b_dW1, 3 * Hn, Hn,
        phi_f, b_dW1 + Hn, 3 * Hn, Hn,
        hc, b_dW1 + 2 * Hn, 3 * Hn, Hn,
        db1, dtmp, Hn);
    gemm_bf16<1, true><<<gBH, blk, 0, stream>>>(
        dtmp, b_dW2, Hn, Hn, nullptr, nullptr, 0, 0, nullptr, nullptr, 0, 0,
        db2, dec, Hn);
    dec_nll_bf16<<<dim3((Xn + 63) / 64, Bn / 64), blk, 0, stream>>>(
        dec, b_dmW, dmb, x + (size_t)t * Bn * Xn, out + 2);
    gru_bf16<3><<<gBH, blk, 0, stream>>>(
        px_t, phiz, phi_f,
        b_rWih, 3 * Hn, hc, b_rWhh, rbih, rbhh, hb);
    us* sw = hc; hc = hb; hb = sw;
  }
}